// Round 16
// baseline (23.952 us; speedup 1.0000x reference)
//
#include <hip/hip_runtime.h>

// Barnes-Wall Lambda16 quantizer — R15 + zero-LDS eval (popcount codebook)
// + epilogue scaling. Removes the last memory ops from the hot path:
// R15's divergent Cs[kk][.] float4 reads were 712K bank-conflict cycles
// (row stride 64B -> banks {0,16} only) plus a pass-1-dependent lgkm chain.
//
// Pass 1 (surrogate, fully unrolled, zero memory ops — R14/R15-validated):
//   ssum: WHT — s = k0 ? S1 - h[kappa] : S0 + h[kappa]
//   mx:   butterfly max-DP — mx(2kap)=T[kap], mx(2kap+1)=S[kap]
//   par:  PAR32 word, per-k shift+and
//   Dtil = s + par*(1-2mx); stable top-3 (strict <, earlier k wins ties).
//
// Pass 2 (bit-exact numpy pipeline, R2..R15-verified; merged emit):
//   cf_j = (float)popcount(kk & m_j)  (R7..R10-proven form, 3 VALU/coord,
//   no LDS). 3 eval_k calls emit unscaled Xp; running winner by
//   lexicographic (D,k) == numpy first-min via cndmask; epilogue scales
//   by a once (y = Xp*a commutes with the select — bit-identical).
//
// Pass-2 bit-exactness invariants (absmax must be 0.0):
//  - fp contract OFF; fmaf only where exact or single-rounding-identical:
//    fmaf(c,-0.5,xh) == fl(xh-c/2); fmaf(2,f,c) exact; Xp=fmaf(bit,+-2,X)
//    exact; e = fmaf(-2,xh,Xp) == fl(Xp-x) single rounding (x=2*xh exact).
//  - rintf == round-half-to-even == np.round; dd = x2 - f exact.
//  - first-max: contiguous-pair tournament, left wins ties (>=).
//  - parity (pass-2): float sum-tree of integer-valued f (exact), cvt, &1.
//  - D in numpy's n=16 pairwise order:
//    r[j]=sq[j]+sq[j+8]; D=((r0+r1)+(r2+r3))+((r4+r5)+(r6+r7)).
//
// Register budget ((256,2) -> ~128 target; rule confirmed R3/R9/R13/R15):
// pass-1 live ~73, pass-2 peak ~100. Gates: VGPR 90-110, FETCH ~8.3 MB,
// WRITE ~16.4 MB, SQ_LDS_BANK_CONFLICT = 0, LDS = 0.

constexpr int G5[5][16] = {
    {1,1,1,1,0,1,0,1,1,0,0,1,0,0,0,0},
    {0,1,1,1,1,0,1,0,1,1,0,0,1,0,0,0},
    {0,0,1,1,1,1,0,1,0,1,1,0,0,1,0,0},
    {0,0,0,1,1,1,1,0,1,0,1,1,0,0,1,0},
    {1,1,1,1,1,1,1,1,1,1,1,1,1,1,1,1}};

struct Tabs {
  int m[16];        // column bit-masks: c_j(k) = popcount(k & m[j])
  int pt[16];       // pt[j] = 4-bit point (rows 0..3 at column j), bijective
  unsigned rowm[5]; // Row_i as bitmask over j
  unsigned par2w;   // bit k = par2(k) = XOR_j (c_j(k)>>1)&1
};
constexpr Tabs make_tabs() {
  Tabs t{};
  for (int j = 0; j < 16; ++j) {
    int m = 0;
    for (int i = 0; i < 5; ++i) m |= G5[i][j] << (4 - i);
    t.m[j] = m;
    t.pt[j] = (G5[0][j] << 3) | (G5[1][j] << 2) | (G5[2][j] << 1) | G5[3][j];
  }
  for (int i = 0; i < 5; ++i) {
    unsigned rm = 0;
    for (int j = 0; j < 16; ++j) rm |= (unsigned)G5[i][j] << j;
    t.rowm[i] = rm;
  }
  t.par2w = 0;
  for (int k = 0; k < 32; ++k) {
    unsigned p2 = 0;
    for (int j = 0; j < 16; ++j) {
      int c = 0;
      for (int i = 0; i < 5; ++i) c += ((k >> (4 - i)) & 1) * G5[i][j];
      p2 ^= (unsigned)((c >> 1) & 1);
    }
    t.par2w |= p2 << k;
  }
  return t;
}
constexpr Tabs tb = make_tabs();

__device__ __forceinline__ int parity16i(const float (&f)[16]) {
  // exact: all addends are small integers
  float s0 = ((f[0] + f[1]) + (f[2] + f[3])) + ((f[4] + f[5]) + (f[6] + f[7]));
  float s1 = ((f[8] + f[9]) + (f[10] + f[11])) + ((f[12] + f[13]) + (f[14] + f[15]));
  return ((int)(s0 + s1)) & 1;
}

// Exact numpy-pipeline evaluation of candidate kk (R2..R15-verified).
// Codeword via popcount (no LDS). Emits UNSCALED Xp into y.
__device__ __forceinline__ float eval_k(int kk, const float (&xh)[16],
                                        float (&y)[16]) {
#pragma clang fp contract(off)
  float cf[16], f[16], dd[16];
#pragma unroll
  for (int j = 0; j < 16; ++j) {
    cf[j] = (float)__builtin_popcount(kk & tb.m[j]);
    float x2 = __builtin_fmaf(cf[j], -0.5f, xh[j]);  // == fl(xh - c/2)
    float fj = __builtin_rintf(x2);
    f[j] = fj;
    dd[j] = x2 - fj;                                 // exact
  }
  const int par = parity16i(f);

  // first-occurrence argmax of |dd| -> onehot (left wins ties)
  float tv[16];
  int ti[16];
#pragma unroll
  for (int j = 0; j < 16; ++j) { tv[j] = __builtin_fabsf(dd[j]); ti[j] = 1 << j; }
#pragma unroll
  for (int w = 8; w >= 1; w >>= 1) {
#pragma unroll
    for (int j = 0; j < w; ++j) {
      bool L = tv[2 * j] >= tv[2 * j + 1];
      tv[j] = L ? tv[2 * j] : tv[2 * j + 1];
      ti[j] = L ? ti[2 * j] : ti[2 * j + 1];
    }
  }
  const int ohm = par ? ti[0] : 0;   // patch mask (0 when parity even)

  float sq[16];
#pragma unroll
  for (int j = 0; j < 16; ++j) {
    float X  = __builtin_fmaf(2.0f, f[j], cf[j]);      // exact int
    float s2 = __builtin_copysignf(2.0f, dd[j]);       // corr direction
    float bitf = (float)((ohm >> j) & 1);
    float Xp = __builtin_fmaf(bitf, s2, X);            // exact int
    float e  = __builtin_fmaf(-2.0f, xh[j], Xp);       // == fl(Xp - x)
    sq[j] = e * e;
    y[j] = Xp;                                         // unscaled
  }
  float r0 = sq[0] + sq[8],  r1 = sq[1] + sq[9];
  float r2 = sq[2] + sq[10], r3 = sq[3] + sq[11];
  float r4 = sq[4] + sq[12], r5 = sq[5] + sq[13];
  float r6 = sq[6] + sq[14], r7 = sq[7] + sq[15];
  return ((r0 + r1) + (r2 + r3)) + ((r4 + r5) + (r6 + r7));
}

__global__ __launch_bounds__(256, 2) void bw_quant_kernel(
    const float* __restrict__ x_in,
    const float* __restrict__ C_rep,   // unused (constexpr codebook)
    const float* __restrict__ a_ptr,
    float* __restrict__ y_out,
    int n_rows)
{
#pragma clang fp contract(off)
  const int row = blockIdx.x * 256 + threadIdx.x;
  if (row >= n_rows) return;

  const float a = a_ptr[0];

  // -------- prologue: xh + residuals -> T/S/g/sq0 by point, parity masks --
  float xh[16], g[16], sq0[16], T[16], S[16];
  int P0 = 0, P1 = 0;
  {
    const float4* xr4 = reinterpret_cast<const float4*>(x_in + (size_t)row * 16);
    float xv[16];
#pragma unroll
    for (int q = 0; q < 4; ++q) {
      float4 v = xr4[q];
      xv[q * 4 + 0] = v.x; xv[q * 4 + 1] = v.y;
      xv[q * 4 + 2] = v.z; xv[q * 4 + 3] = v.w;
    }
#pragma unroll
    for (int j = 0; j < 16; ++j) {
      float xj = xv[j] / a;
      float xhj = xj * 0.5f;                // exact
      xh[j] = xhj;                          // live through both passes
      float t0 = __builtin_rintf(xhj);
      float d0 = xhj - t0;                  // exact
      float hm = xhj - 0.5f;
      float t1 = __builtin_rintf(hm);
      float d1 = hm - t1;                   // exact
      P0 |= ((int)t0 & 1) << j;
      P1 |= ((int)t1 & 1) << j;
      sq0[j] = d0 * d0;
      g[tb.pt[j]] = __builtin_fmaf(d1, d1, -sq0[j]);  // delta by point
      T[tb.pt[j]] = __builtin_fabsf(d0);              // u by point
      S[tb.pt[j]] = __builtin_fabsf(d1);              // w by point
    }
  }
  float S0 = (((sq0[0] + sq0[1]) + (sq0[2] + sq0[3])) + ((sq0[4] + sq0[5]) + (sq0[6] + sq0[7])))
           + (((sq0[8] + sq0[9]) + (sq0[10] + sq0[11])) + ((sq0[12] + sq0[13]) + (sq0[14] + sq0[15])));

  // fast WHT on g (ssum path, R11/R14/R15-validated)
#pragma unroll
  for (int st = 1; st < 16; st <<= 1) {
#pragma unroll
    for (int p = 0; p < 16; ++p) {
      if (!(p & st)) {
        float u = g[p], v = g[p | st];
        g[p] = u + v;
        g[p | st] = u - v;
      }
    }
  }
  float S1 = S0 + g[0];
  float h[16];
  h[0] = 0.0f;
#pragma unroll
  for (int t = 1; t < 16; ++t) h[t] = 0.5f * (g[0] - g[t]);

  // butterfly max-DP (R12/R14/R15-validated)
#pragma unroll
  for (int st = 1; st < 16; st <<= 1) {
#pragma unroll
    for (int p = 0; p < 16; ++p) {
      if (!(p & st)) {
        float tA = T[p], tB = T[p | st];
        float sA = S[p], sB = S[p | st];
        T[p]      = __builtin_fmaxf(tA, tB);
        T[p | st] = __builtin_fmaxf(tA, sB);
        S[p]      = __builtin_fmaxf(sA, sB);
        S[p | st] = __builtin_fmaxf(sA, tB);
      }
    }
  }

  // PAR32 (R12/R14/R15-validated): bit k = surrogate parity of candidate k
  unsigned PAR;
  {
    unsigned Q = (unsigned)(P0 ^ P1);
    PAR = ((__builtin_popcount((unsigned)P0) & 1) ? 0xFFFFFFFFu : 0u) ^ tb.par2w;
    PAR ^= ((__builtin_popcount(Q & tb.rowm[0]) & 1) ? 0xFFFF0000u : 0u);  // k bit 4
    PAR ^= ((__builtin_popcount(Q & tb.rowm[1]) & 1) ? 0xFF00FF00u : 0u);  // k bit 3
    PAR ^= ((__builtin_popcount(Q & tb.rowm[2]) & 1) ? 0xF0F0F0F0u : 0u);  // k bit 2
    PAR ^= ((__builtin_popcount(Q & tb.rowm[3]) & 1) ? 0xCCCCCCCCu : 0u);  // k bit 1
    PAR ^= ((__builtin_popcount(Q & tb.rowm[4]) & 1) ? 0xAAAAAAAAu : 0u);  // k bit 0
  }

  // -------- pass 1: fully unrolled surrogate ranking, stable top-3 --------
  float b1 = __builtin_inff(), b2 = b1, b3 = b1;
  int k1 = 0, k2 = 0, k3 = 0;

#pragma unroll
  for (int k = 0; k < 32; ++k) {
    const int kap = k >> 1;
    float s  = (k & 1) ? (S1 - h[kap]) : (S0 + h[kap]);   // WHT ssum
    float mx = (k & 1) ? S[kap] : T[kap];                 // DP max (register)
    float spen = s + __builtin_fmaf(-2.0f, mx, 1.0f);
    float dtil = ((PAR >> k) & 1u) ? spen : s;

    // stable top-3 insert (strict <: earlier k wins ties)
    bool lt1 = dtil < b1, lt2 = dtil < b2, lt3 = dtil < b3;
    float nb3 = lt3 ? (lt2 ? b2 : dtil) : b3;  int nk3 = lt3 ? (lt2 ? k2 : k) : k3;
    float nb2 = lt2 ? (lt1 ? b1 : dtil) : b2;  int nk2 = lt2 ? (lt1 ? k1 : k) : k2;
    b3 = nb3; k3 = nk3;
    b2 = nb2; k2 = nk2;
    b1 = lt1 ? dtil : b1;  k1 = lt1 ? k : k1;
  }

  // -------- pass 2: exact evals with running winner (merged emit) ---------
  float yb[16], yt[16];
  float Db = eval_k(k1, xh, yb);
  int kb = k1;
  {
    float D2 = eval_k(k2, xh, yt);
    bool c2 = (D2 < Db) || (D2 == Db && k2 < kb);
    Db = c2 ? D2 : Db; kb = c2 ? k2 : kb;
#pragma unroll
    for (int j = 0; j < 16; ++j) yb[j] = c2 ? yt[j] : yb[j];
  }
  {
    float D3 = eval_k(k3, xh, yt);
    bool c3 = (D3 < Db) || (D3 == Db && k3 < kb);
#pragma unroll
    for (int j = 0; j < 16; ++j) yb[j] = c3 ? yt[j] : yb[j];
  }

  float4* yr4 = reinterpret_cast<float4*>(y_out + (size_t)row * 16);
#pragma unroll
  for (int q = 0; q < 4; ++q) {
    float4 v;
    v.x = yb[q * 4 + 0] * a; v.y = yb[q * 4 + 1] * a;
    v.z = yb[q * 4 + 2] * a; v.w = yb[q * 4 + 3] * a;
    yr4[q] = v;
  }
}

extern "C" void kernel_launch(void* const* d_in, const int* in_sizes, int n_in,
                              void* d_out, int out_size, void* d_ws, size_t ws_size,
                              hipStream_t stream) {
  const float* x_in  = (const float*)d_in[0];
  const float* C_rep = (const float*)d_in[1];
  const float* a_ptr = (const float*)d_in[2];
  float* y_out = (float*)d_out;

  const int n_rows = in_sizes[0] / 16;
  const int block = 256;
  const int grid = (n_rows + block - 1) / block;
  bw_quant_kernel<<<grid, block, 0, stream>>>(x_in, C_rep, a_ptr, y_out, n_rows);
}